// Round 5
// baseline (411.629 us; speedup 1.0000x reference)
//
#include <hip/hip_runtime.h>
#include <hip/hip_bf16.h>

#define NPD 30000        // atoms per degree bucket
#define NF  128          // feature dim == filter dim
#define MAXDEG 6
#define TM  64           // output tile rows per block (one 64x128 tile, 4 waves)

typedef __attribute__((ext_vector_type(8))) short short8;   // 8 x bf16 (4 VGPRs)
typedef __attribute__((ext_vector_type(4))) float floatx4;  // MFMA accumulator

__device__ __forceinline__ unsigned short f2bf(float f) {
    __hip_bfloat16 h = __float2bfloat16(f);
    return __builtin_bit_cast(unsigned short, h);
}
__device__ __forceinline__ short8 pack8(float4 a, float4 b) {
    short8 r;
    r[0] = (short)f2bf(a.x); r[1] = (short)f2bf(a.y);
    r[2] = (short)f2bf(a.z); r[3] = (short)f2bf(a.w);
    r[4] = (short)f2bf(b.x); r[5] = (short)f2bf(b.y);
    r[6] = (short)f2bf(b.z); r[7] = (short)f2bf(b.w);
    return r;
}

// ---- W transpose + convert: W[a][k][n] fp32 -> Wt[a][n][k] bf16 ----
__global__ void wt_kernel(const float* __restrict__ W,
                          unsigned short* __restrict__ Wt) {
    __shared__ unsigned short t[32][33];
    const int a  = blockIdx.z;
    const int k0 = blockIdx.x * 32, n0 = blockIdx.y * 32;
    const int tx = threadIdx.x & 31, ty = threadIdx.x >> 5;  // 256 thr: 32x8
    const float*    Wp  = W  + (size_t)a * NF * NF;
    unsigned short* Wtp = Wt + (size_t)a * NF * NF;
#pragma unroll
    for (int i = 0; i < 32; i += 8)
        t[ty + i][tx] = f2bf(Wp[(size_t)(k0 + ty + i) * NF + (n0 + tx)]);
    __syncthreads();
#pragma unroll
    for (int i = 0; i < 32; i += 8)
        Wtp[(size_t)(n0 + ty + i) * NF + (k0 + tx)] = t[tx][ty + i];
}

// ---- B-fragment loads for one affine slab (32 cols x full K) ----
__device__ __forceinline__ void load_bfrags(short8 b[4][2],
                                            const float* __restrict__ Wf,
                                            const unsigned short* __restrict__ Wt,
                                            int use_wt, int wi, int col0, int nb, int kq) {
    if (use_wt) {
        const unsigned short* Wp = Wt + (size_t)wi * NF * NF;
#pragma unroll
        for (int kk = 0; kk < 4; ++kk)
#pragma unroll
            for (int nt = 0; nt < 2; ++nt)
                b[kk][nt] = *(const short8*)(Wp + (size_t)(col0 + nt * 16 + nb) * NF
                                             + kk * 32 + kq);
    } else {
        const float* Wp = Wf + (size_t)wi * NF * NF;
#pragma unroll
        for (int kk = 0; kk < 4; ++kk)
#pragma unroll
            for (int nt = 0; nt < 2; ++nt) {
                short8 f;
#pragma unroll
                for (int j = 0; j < 8; ++j)
                    f[j] = (short)f2bf(Wp[(size_t)(kk * 32 + kq + j) * NF
                                          + (col0 + nt * 16 + nb)]);
                b[kk][nt] = f;
            }
    }
}

// ---- per-wave worker: 64 rows x 32 cols, no LDS, no barriers ----
template <int DEG>
__device__ __forceinline__ void wave_work(
    const float* __restrict__ atoms, const float* __restrict__ W,
    const unsigned short* __restrict__ Wt, const float* __restrict__ bvec,
    const int* __restrict__ adj, int use_wt,
    float* __restrict__ out, int row0, int lane, int wave)
{
    const int nb   = lane & 15;          // row (A) / col (B,C) within 16-tile
    const int kq   = (lane >> 4) * 8;    // k-offset within 32-slice
    const int col0 = wave * 32;
    const int wi_self = (DEG == 0) ? 12 : (2 * DEG - 1);
    const int wi_rel  = (DEG > 0) ? 2 * (DEG - 1) : 0;

    floatx4 acc[4][2];
#pragma unroll
    for (int i = 0; i < 4; i++)
#pragma unroll
        for (int j = 0; j < 2; j++) acc[i][j] = (floatx4){0.f, 0.f, 0.f, 0.f};

    // ---- self phase: contiguous rows, direct-to-fragment ----
    {
        short8 bS[4][2];
        load_bfrags(bS, W, Wt, use_wt, wi_self, col0, nb, kq);
#pragma unroll
        for (int mt = 0; mt < 4; ++mt) {
            const int rl = min(row0 + mt * 16 + nb, NPD - 1);
            const float* row = atoms + (size_t)(DEG * NPD + rl) * NF;
#pragma unroll
            for (int kk = 0; kk < 4; ++kk) {
                const float4* p = (const float4*)(row + kk * 32 + kq);
                float4 v0 = p[0], v1 = p[1];
                short8 a = pack8(v0, v1);
#pragma unroll
                for (int nt = 0; nt < 2; ++nt)
                    acc[mt][nt] = __builtin_amdgcn_mfma_f32_16x16x32_bf16(
                        a, bS[kk][nt], acc[mt][nt], 0, 0, 0);
            }
        }
    }

    // ---- rel phase: gather-sum direct-to-fragment ----
    if constexpr (DEG > 0) {
        short8 bR[4][2];
        load_bfrags(bR, W, Wt, use_wt, wi_rel, col0, nb, kq);
#pragma unroll
        for (int mt = 0; mt < 4; ++mt) {
            const int rl = min(row0 + mt * 16 + nb, NPD - 1);
            const int* ar = adj + (size_t)rl * DEG;
            int idxs[DEG];
#pragma unroll
            for (int j = 0; j < DEG; ++j) idxs[j] = ar[j];
#pragma unroll
            for (int kk = 0; kk < 4; ++kk) {
                float s[8] = {0.f, 0.f, 0.f, 0.f, 0.f, 0.f, 0.f, 0.f};
#pragma unroll
                for (int j = 0; j < DEG; ++j) {
                    const float4* p = (const float4*)(atoms + (size_t)idxs[j] * NF
                                                      + kk * 32 + kq);
                    float4 v0 = p[0], v1 = p[1];
                    s[0] += v0.x; s[1] += v0.y; s[2] += v0.z; s[3] += v0.w;
                    s[4] += v1.x; s[5] += v1.y; s[6] += v1.z; s[7] += v1.w;
                }
                short8 a;
#pragma unroll
                for (int i = 0; i < 8; ++i) a[i] = (short)f2bf(s[i]);
#pragma unroll
                for (int nt = 0; nt < 2; ++nt)
                    acc[mt][nt] = __builtin_amdgcn_mfma_f32_16x16x32_bf16(
                        a, bR[kk][nt], acc[mt][nt], 0, 0, 0);
            }
        }
    }

    // ---- epilogue: bias + fp32 store ----
    float bias[2];
#pragma unroll
    for (int nt = 0; nt < 2; ++nt) {
        const int n = col0 + nt * 16 + nb;
        float bv = bvec[wi_self * NF + n];
        if (DEG > 0) bv += bvec[wi_rel * NF + n];
        bias[nt] = bv;
    }
    const int rq = (lane >> 4) * 4;
#pragma unroll
    for (int mt = 0; mt < 4; ++mt) {
#pragma unroll
        for (int reg = 0; reg < 4; ++reg) {
            const int r = row0 + mt * 16 + rq + reg;
            if (r < NPD) {
                float* op = out + (size_t)(DEG * NPD + r) * NF;
#pragma unroll
                for (int nt = 0; nt < 2; ++nt)
                    op[col0 + nt * 16 + nb] = acc[mt][nt][reg] + bias[nt];
            }
        }
    }
}

__global__ __launch_bounds__(256) void gconv_kernel(
    const float* __restrict__ atoms, const float* __restrict__ W,
    const unsigned short* __restrict__ Wt, const float* __restrict__ bvec,
    const int* __restrict__ adj1, const int* __restrict__ adj2,
    const int* __restrict__ adj3, const int* __restrict__ adj4,
    const int* __restrict__ adj5, const int* __restrict__ adj6,
    const int use_wt, float* __restrict__ out)
{
    const int lane = threadIdx.x & 63;
    const int wave = threadIdx.x >> 6;
    const int row0 = blockIdx.x * TM;
    switch (blockIdx.y) {
        case 0: wave_work<0>(atoms, W, Wt, bvec, nullptr, use_wt, out, row0, lane, wave); break;
        case 1: wave_work<1>(atoms, W, Wt, bvec, adj1,    use_wt, out, row0, lane, wave); break;
        case 2: wave_work<2>(atoms, W, Wt, bvec, adj2,    use_wt, out, row0, lane, wave); break;
        case 3: wave_work<3>(atoms, W, Wt, bvec, adj3,    use_wt, out, row0, lane, wave); break;
        case 4: wave_work<4>(atoms, W, Wt, bvec, adj4,    use_wt, out, row0, lane, wave); break;
        case 5: wave_work<5>(atoms, W, Wt, bvec, adj5,    use_wt, out, row0, lane, wave); break;
        default: wave_work<6>(atoms, W, Wt, bvec, adj6,   use_wt, out, row0, lane, wave); break;
    }
}

extern "C" void kernel_launch(void* const* d_in, const int* in_sizes, int n_in,
                              void* d_out, int out_size, void* d_ws, size_t ws_size,
                              hipStream_t stream) {
    const float* atoms = (const float*)d_in[0];
    const float* W     = (const float*)d_in[1];
    const float* b     = (const float*)d_in[2];
    // d_in[3] = deg_slice (static, unused)
    const int* adj1 = (const int*)d_in[4];
    const int* adj2 = (const int*)d_in[5];
    const int* adj3 = (const int*)d_in[6];
    const int* adj4 = (const int*)d_in[7];
    const int* adj5 = (const int*)d_in[8];
    const int* adj6 = (const int*)d_in[9];

    const size_t wt_bytes = (size_t)13 * NF * NF * sizeof(unsigned short);  // 425984
    const int use_wt = (ws_size >= wt_bytes) ? 1 : 0;
    unsigned short* Wt = (unsigned short*)d_ws;

    if (use_wt)
        wt_kernel<<<dim3(4, 4, 13), 256, 0, stream>>>(W, Wt);
    gconv_kernel<<<dim3((NPD + TM - 1) / TM, MAXDEG + 1), 256, 0, stream>>>(
        atoms, W, Wt, b, adj1, adj2, adj3, adj4, adj5, adj6, use_wt,
        (float*)d_out);
}

// Round 6
// 274.827 us; speedup vs baseline: 1.4978x; 1.4978x over previous
//
#include <hip/hip_runtime.h>
#include <hip/hip_bf16.h>

#define NPD 30000        // atoms per degree bucket
#define NF  128          // feature dim == filter dim
#define MAXDEG 6
#define TM  64           // output tile rows per block
#define LDK 136          // padded LDS leading dim (bf16 elems)

typedef __attribute__((ext_vector_type(8))) short short8;   // 8 x bf16 (4 VGPRs)
typedef __attribute__((ext_vector_type(4))) float floatx4;  // MFMA accumulator

__device__ __forceinline__ unsigned short f2bf(float f) {
    __hip_bfloat16 h = __float2bfloat16(f);
    return __builtin_bit_cast(unsigned short, h);
}
__device__ __forceinline__ float bf2f(unsigned short u) {
    unsigned v = ((unsigned)u) << 16; return __builtin_bit_cast(float, v);
}
__device__ __forceinline__ uint4 pack16B(float4 a, float4 b) {
    uint4 v;
    v.x = (unsigned)f2bf(a.x) | ((unsigned)f2bf(a.y) << 16);
    v.y = (unsigned)f2bf(a.z) | ((unsigned)f2bf(a.w) << 16);
    v.z = (unsigned)f2bf(b.x) | ((unsigned)f2bf(b.y) << 16);
    v.w = (unsigned)f2bf(b.z) | ((unsigned)f2bf(b.w) << 16);
    return v;
}
__device__ __forceinline__ void addu4(float* s, uint4 h) {
    s[0] += bf2f((unsigned short)h.x); s[1] += bf2f((unsigned short)(h.x >> 16));
    s[2] += bf2f((unsigned short)h.y); s[3] += bf2f((unsigned short)(h.y >> 16));
    s[4] += bf2f((unsigned short)h.z); s[5] += bf2f((unsigned short)(h.z >> 16));
    s[6] += bf2f((unsigned short)h.w); s[7] += bf2f((unsigned short)(h.w >> 16));
}

// ---- W transpose + convert: W[a][k][n] fp32 -> Wt[a][n][k] bf16 ----
__global__ void wt_kernel(const float* __restrict__ W,
                          unsigned short* __restrict__ Wt) {
    __shared__ unsigned short t[32][33];
    const int a  = blockIdx.z;
    const int k0 = blockIdx.x * 32, n0 = blockIdx.y * 32;
    const int tx = threadIdx.x & 31, ty = threadIdx.x >> 5;  // 256 thr: 32x8
    const float*    Wp  = W  + (size_t)a * NF * NF;
    unsigned short* Wtp = Wt + (size_t)a * NF * NF;
#pragma unroll
    for (int i = 0; i < 32; i += 8)
        t[ty + i][tx] = f2bf(Wp[(size_t)(k0 + ty + i) * NF + (n0 + tx)]);
    __syncthreads();
#pragma unroll
    for (int i = 0; i < 32; i += 8)
        Wtp[(size_t)(n0 + ty + i) * NF + (k0 + tx)] = t[tx][ty + i];
}

// ---- atoms fp32 -> bf16 mirror (pure streaming) ----
__global__ __launch_bounds__(256) void cvt_kernel(const float* __restrict__ src,
                                                  unsigned short* __restrict__ dst) {
    const size_t i = (size_t)blockIdx.x * 256 + threadIdx.x;   // one 16B chunk = 8 elems
    const size_t n8 = (size_t)NPD * (MAXDEG + 1) * NF / 8;
    if (i < n8) {
        const float4* p = (const float4*)(src + i * 8);
        ((uint4*)dst)[i] = pack16B(p[0], p[1]);
    }
}

// ---- B-fragments for one kk slice: 4 col-tiles x 32k ----
__device__ __forceinline__ void load_bfr(short8 b[4], const float* __restrict__ Wf,
                                         const unsigned short* __restrict__ Wt,
                                         int use_wt, int wi, int kk,
                                         int col0, int nb, int kq) {
    if (use_wt) {
        const unsigned short* Wp = Wt + (size_t)wi * NF * NF;
#pragma unroll
        for (int nt = 0; nt < 4; ++nt)
            b[nt] = *(const short8*)(Wp + (size_t)(col0 + nt * 16 + nb) * NF + kk * 32 + kq);
    } else {
        const float* Wp = Wf + (size_t)wi * NF * NF;
#pragma unroll
        for (int nt = 0; nt < 4; ++nt) {
            short8 f;
#pragma unroll
            for (int j = 0; j < 8; ++j)
                f[j] = (short)f2bf(Wp[(size_t)(kk * 32 + kq + j) * NF + col0 + nt * 16 + nb]);
            b[nt] = f;
        }
    }
}

template <int DEG, bool BF16A>
__device__ __forceinline__ void degree_work(
    const float* __restrict__ atomsF, const unsigned short* __restrict__ atomsH,
    const float* __restrict__ W, const unsigned short* __restrict__ Wt,
    const float* __restrict__ bvec, const int* __restrict__ adj,
    int use_wt, float* __restrict__ out,
    unsigned short* sA, int* sIdx)
{
    const int tid  = threadIdx.x;
    const int lane = tid & 63, wave = tid >> 6;
    const int wr = wave >> 1, wc = wave & 1;     // 2x2 waves over 64x128 tile
    const int row0_local = blockIdx.x * TM;
    const int valid = min(TM, NPD - row0_local);
    const int row0g = DEG * NPD + row0_local;
    const int nb = lane & 15;
    const int kq = (lane >> 4) * 8;
    const int col0 = wc * 64;
    const int wi_self = (DEG == 0) ? 12 : (2 * DEG - 1);
    const int wi_rel  = (DEG > 0) ? 2 * (DEG - 1) : 0;

    floatx4 acc[2][4];
#pragma unroll
    for (int i = 0; i < 2; i++)
#pragma unroll
        for (int j = 0; j < 4; j++) acc[i][j] = (floatx4){0.f, 0.f, 0.f, 0.f};

    // stage this tile's adjacency rows into LDS (contiguous in adj -> coalesced)
    if (DEG > 0) {
        for (int i = tid; i < valid * DEG; i += 256)
            sIdx[i] = adj[(size_t)row0_local * DEG + i];
    }

    // ---- phase-1 staging: self rows -> sA bf16 (coalesced 16B chunks) ----
#pragma unroll
    for (int p = 0; p < 4; ++p) {
        int idx = p * 256 + tid;
        int r = idx >> 4, ch = (idx & 15) * 8;
        int rr = min(r, valid - 1);
        uint4 v;
        if (BF16A) {
            v = *(const uint4*)(atomsH + (size_t)(row0g + rr) * NF + ch);
        } else {
            const float4* pf = (const float4*)(atomsF + (size_t)(row0g + rr) * NF + ch);
            v = pack16B(pf[0], pf[1]);
        }
        *(uint4*)&sA[r * LDK + ch] = v;
    }
    __syncthreads();

    auto run_phase = [&](int wi) {
#pragma unroll
        for (int kk = 0; kk < 4; ++kk) {
            short8 bfr[4];
            load_bfr(bfr, W, Wt, use_wt, wi, kk, col0, nb, kq);
            short8 af[2];
#pragma unroll
            for (int mt = 0; mt < 2; ++mt)
                af[mt] = *(const short8*)&sA[(wr * 32 + mt * 16 + nb) * LDK + kk * 32 + kq];
#pragma unroll
            for (int mt = 0; mt < 2; ++mt)
#pragma unroll
                for (int nt = 0; nt < 4; ++nt)
                    acc[mt][nt] = __builtin_amdgcn_mfma_f32_16x16x32_bf16(
                        af[mt], bfr[nt], acc[mt][nt], 0, 0, 0);
        }
    };

    run_phase(wi_self);

    // ---- phase 2: gathered neighbor sums (indices from LDS, DEG unrolled) ----
    if constexpr (DEG > 0) {
        __syncthreads();   // everyone done reading phase-1 sA
#pragma unroll
        for (int p = 0; p < 2; ++p) {
            int idx = p * 256 + tid;
            int r = idx >> 3, kc = (idx & 7) * 16;   // 8 thr/row, 16 cols each
            int rr = min(r, valid - 1);
            int idxs[DEG];
#pragma unroll
            for (int j = 0; j < DEG; ++j) idxs[j] = sIdx[rr * DEG + j];
            float s[16];
#pragma unroll
            for (int i = 0; i < 16; ++i) s[i] = 0.f;
#pragma unroll
            for (int j = 0; j < DEG; ++j) {
                if (BF16A) {
                    const uint4* ph = (const uint4*)(atomsH + (size_t)idxs[j] * NF + kc);
                    uint4 h0 = ph[0], h1 = ph[1];
                    addu4(s, h0); addu4(s + 8, h1);
                } else {
                    const float4* pf = (const float4*)(atomsF + (size_t)idxs[j] * NF + kc);
                    float4 q0 = pf[0], q1 = pf[1], q2 = pf[2], q3 = pf[3];
                    s[0]  += q0.x; s[1]  += q0.y; s[2]  += q0.z; s[3]  += q0.w;
                    s[4]  += q1.x; s[5]  += q1.y; s[6]  += q1.z; s[7]  += q1.w;
                    s[8]  += q2.x; s[9]  += q2.y; s[10] += q2.z; s[11] += q2.w;
                    s[12] += q3.x; s[13] += q3.y; s[14] += q3.z; s[15] += q3.w;
                }
            }
            uint4 w0, w1;
            w0.x = (unsigned)f2bf(s[0])  | ((unsigned)f2bf(s[1])  << 16);
            w0.y = (unsigned)f2bf(s[2])  | ((unsigned)f2bf(s[3])  << 16);
            w0.z = (unsigned)f2bf(s[4])  | ((unsigned)f2bf(s[5])  << 16);
            w0.w = (unsigned)f2bf(s[6])  | ((unsigned)f2bf(s[7])  << 16);
            w1.x = (unsigned)f2bf(s[8])  | ((unsigned)f2bf(s[9])  << 16);
            w1.y = (unsigned)f2bf(s[10]) | ((unsigned)f2bf(s[11]) << 16);
            w1.z = (unsigned)f2bf(s[12]) | ((unsigned)f2bf(s[13]) << 16);
            w1.w = (unsigned)f2bf(s[14]) | ((unsigned)f2bf(s[15]) << 16);
            *(uint4*)&sA[r * LDK + kc]     = w0;
            *(uint4*)&sA[r * LDK + kc + 8] = w1;
        }
        __syncthreads();
        run_phase(wi_rel);
    }

    // ---- epilogue: bias + fp32 store ----
    float bias[4];
#pragma unroll
    for (int nt = 0; nt < 4; ++nt) {
        const int n = col0 + nt * 16 + nb;
        float bv = bvec[wi_self * NF + n];
        if (DEG > 0) bv += bvec[wi_rel * NF + n];
        bias[nt] = bv;
    }
    const int rq = (lane >> 4) * 4;
#pragma unroll
    for (int mt = 0; mt < 2; ++mt) {
#pragma unroll
        for (int reg = 0; reg < 4; ++reg) {
            const int r = wr * 32 + mt * 16 + rq + reg;
            if (r < valid) {
                float* op = out + (size_t)(row0g + r) * NF;
#pragma unroll
                for (int nt = 0; nt < 4; ++nt)
                    op[col0 + nt * 16 + nb] = acc[mt][nt][reg] + bias[nt];
            }
        }
    }
}

template <bool BF16A>
__global__ __launch_bounds__(256) void gconv_kernel(
    const float* __restrict__ atomsF, const unsigned short* __restrict__ atomsH,
    const float* __restrict__ W, const unsigned short* __restrict__ Wt,
    const float* __restrict__ bvec,
    const int* __restrict__ adj1, const int* __restrict__ adj2,
    const int* __restrict__ adj3, const int* __restrict__ adj4,
    const int* __restrict__ adj5, const int* __restrict__ adj6,
    const int use_wt, float* __restrict__ out)
{
    __shared__ unsigned short sA[TM * LDK];   // 17408 B
    __shared__ int sIdx[TM * MAXDEG];         //  1536 B
    switch (blockIdx.y) {
        case 0: degree_work<0, BF16A>(atomsF, atomsH, W, Wt, bvec, nullptr, use_wt, out, sA, sIdx); break;
        case 1: degree_work<1, BF16A>(atomsF, atomsH, W, Wt, bvec, adj1,    use_wt, out, sA, sIdx); break;
        case 2: degree_work<2, BF16A>(atomsF, atomsH, W, Wt, bvec, adj2,    use_wt, out, sA, sIdx); break;
        case 3: degree_work<3, BF16A>(atomsF, atomsH, W, Wt, bvec, adj3,    use_wt, out, sA, sIdx); break;
        case 4: degree_work<4, BF16A>(atomsF, atomsH, W, Wt, bvec, adj4,    use_wt, out, sA, sIdx); break;
        case 5: degree_work<5, BF16A>(atomsF, atomsH, W, Wt, bvec, adj5,    use_wt, out, sA, sIdx); break;
        default: degree_work<6, BF16A>(atomsF, atomsH, W, Wt, bvec, adj6,   use_wt, out, sA, sIdx); break;
    }
}

extern "C" void kernel_launch(void* const* d_in, const int* in_sizes, int n_in,
                              void* d_out, int out_size, void* d_ws, size_t ws_size,
                              hipStream_t stream) {
    const float* atoms = (const float*)d_in[0];
    const float* W     = (const float*)d_in[1];
    const float* b     = (const float*)d_in[2];
    // d_in[3] = deg_slice (static, unused)
    const int* adj1 = (const int*)d_in[4];
    const int* adj2 = (const int*)d_in[5];
    const int* adj3 = (const int*)d_in[6];
    const int* adj4 = (const int*)d_in[7];
    const int* adj5 = (const int*)d_in[8];
    const int* adj6 = (const int*)d_in[9];

    const size_t wt_bytes = (size_t)13 * NF * NF * sizeof(unsigned short);          // 425984
    const size_t at_bytes = (size_t)NPD * (MAXDEG + 1) * NF * sizeof(unsigned short); // 53.76 MB
    const int use_wt   = (ws_size >= wt_bytes) ? 1 : 0;
    const int use_bf16 = (ws_size >= wt_bytes + at_bytes) ? 1 : 0;
    unsigned short* Wt     = (unsigned short*)d_ws;
    unsigned short* atomsH = (unsigned short*)((char*)d_ws + wt_bytes);

    if (use_wt)
        wt_kernel<<<dim3(4, 4, 13), 256, 0, stream>>>(W, Wt);
    if (use_bf16) {
        const int n8 = NPD * (MAXDEG + 1) * NF / 8;          // 3,360,000
        cvt_kernel<<<(n8 + 255) / 256, 256, 0, stream>>>(atoms, atomsH);
        gconv_kernel<true><<<dim3((NPD + TM - 1) / TM, MAXDEG + 1), 256, 0, stream>>>(
            atoms, atomsH, W, Wt, b, adj1, adj2, adj3, adj4, adj5, adj6, use_wt,
            (float*)d_out);
    } else {
        gconv_kernel<false><<<dim3((NPD + TM - 1) / TM, MAXDEG + 1), 256, 0, stream>>>(
            atoms, atomsH, W, Wt, b, adj1, adj2, adj3, adj4, adj5, adj6, use_wt,
            (float*)d_out);
    }
}